// Round 9
// baseline (93.844 us; speedup 1.0000x reference)
//
#include <hip/hip_runtime.h>

// DKNN via NeuralSort relaxation — round 11 (burst-load phase S).
// query [32,128] f32, neighbors [1024,128] f32, gumbel [2,32,1024] f32.
// out [2,32,1024] f32 = sum of first K=16 rows of relaxed perm matrix.
//
// Numerics FROZEN (absmax pinned at 0.0234375, bf16 compare). Score chain
// (a0..a3 over d4=0..31 ascending), per-quarter B sums, (q0+q1)+(q2+q3)
// combine, k_soft reduction trees: exact R6/R10 orders => bitwise-identical.
//
// R10 post-mortem: phase S was L1-thrash-bound. Per-lane 512-B rows read as
// 32 compute-interleaved float4 loads -> each 64-B line touched 4x with
// long gaps; 16 waves x 64 lines x 64B = 64KB footprint > 32KB L1 -> line
// evicted between touches -> ~4x L2 refetch + 32K unmerged TA transactions
// per CU (~17us). R6's k_scores avoided this with only 4 waves/CU (16KB).
//
// R11 fix: burst-load 16 float4 (quarter... half row, 64 VGPRs) with no
// intervening compute -> the 4 same-line touches issue back-to-back and
// MSHR-merge into ONE L2 fill; then run the frozen chain from registers.
// Two bursts per row keeps data VGPRs at 64 (cap 128 via launch_bounds).

constexpr int NN = 1024;   // neighbors
constexpr int ND = 128;    // dims
constexpr int NP = 64;     // samples(2) * queries(32)
constexpr int KTOP = 16;

// ---------------------------------------------------------------- kernel 1
// Fused scores + B. grid = 64p * 4jc = 256 blocks x 1024 thr (1 block/CU).
__global__ __launch_bounds__(1024, 4) void k_sb3(
    const float* __restrict__ q, const float* __restrict__ nb,
    const float* __restrict__ gum, double* __restrict__ s_out,
    double* __restrict__ b_out) {
  int b = blockIdx.x;
  int p = b >> 2, jc = b & 3;
  int m = p & 31;
  __shared__ double qs[ND];
  __shared__ double ss[NN];
  __shared__ double qarr[NN];
  int tid = threadIdx.x;
  if (tid < ND) qs[tid] = (double)q[m * ND + tid];
  __syncthreads();

  // ---- phase S: burst-load half-row into regs, then frozen chain.
  {
    int i = tid;
    const float4* nrow = (const float4*)(nb + (size_t)i * ND);
    double a0 = 0.0, a1 = 0.0, a2 = 0.0, a3 = 0.0;

    float4 r0[16];
#pragma unroll
    for (int d4 = 0; d4 < 16; ++d4) r0[d4] = nrow[d4];   // burst 1 (64 VGPR)
#pragma unroll
    for (int d4 = 0; d4 < 16; ++d4) {
      float4 n4 = r0[d4];
      double d0 = qs[d4 * 4 + 0] - (double)n4.x;
      double d1 = qs[d4 * 4 + 1] - (double)n4.y;
      double d2 = qs[d4 * 4 + 2] - (double)n4.z;
      double d3 = qs[d4 * 4 + 3] - (double)n4.w;
      a0 += d0 * d0; a1 += d1 * d1; a2 += d2 * d2; a3 += d3 * d3;
    }
    float4 r1[16];
#pragma unroll
    for (int d4 = 16; d4 < 32; ++d4) r1[d4 - 16] = nrow[d4];  // burst 2
#pragma unroll
    for (int d4 = 16; d4 < 32; ++d4) {
      float4 n4 = r1[d4 - 16];
      double d0 = qs[d4 * 4 + 0] - (double)n4.x;
      double d1 = qs[d4 * 4 + 1] - (double)n4.y;
      double d2 = qs[d4 * 4 + 2] - (double)n4.z;
      double d3 = qs[d4 * 4 + 3] - (double)n4.w;
      a0 += d0 * d0; a1 += d1 * d1; a2 += d2 * d2; a3 += d3 * d3;
    }
    ss[i] = (double)gum[(size_t)p * NN + i] - ((a0 + a1) + (a2 + a3));
  }
  __syncthreads();

  // ---- phase B: thread t = (iq = t>>8, jj = t&255) computes the quarter-iq
  // sum for j = jc*256+jj (exact R6 k_bsum inner loop; sq reads broadcast).
  int jj = tid & 255;
  int iq = tid >> 8;
  int j = jc * 256 + jj;
  double sj = ss[j];
  const double* sq = ss + iq * 256;
  double a0 = 0.0, a1 = 0.0, a2 = 0.0, a3 = 0.0;
#pragma unroll 4
  for (int i = 0; i < 256; i += 4) {
    a0 += fabs(sj - sq[i + 0]);
    a1 += fabs(sj - sq[i + 1]);
    a2 += fabs(sj - sq[i + 2]);
    a3 += fabs(sj - sq[i + 3]);
  }
  qarr[tid] = (a0 + a1) + (a2 + a3);
  __syncthreads();

  // ---- combine quarters (frozen (q0+q1)+(q2+q3) order) + write s, B.
  if (tid < 256) {
    double bjv = (qarr[tid] + qarr[tid + 256]) +
                 (qarr[tid + 512] + qarr[tid + 768]);
    size_t gidx = (size_t)p * NN + jc * 256 + tid;
    b_out[gidx] = bjv;
    s_out[gidx] = ss[jc * 256 + tid];
  }
}

// ---------------------------------------------------------------- kernel 2
// Softmax-topk, exact R6 k_soft (2 barriers, batched reductions); bj is a
// single load of the pre-combined B (identical bits to R6's 4-load combine).
__global__ __launch_bounds__(256) void k_soft(const double* __restrict__ s,
                                              const double* __restrict__ B,
                                              float* __restrict__ out) {
  int p = blockIdx.x;
  int tid = threadIdx.x;
  int wave = tid >> 6, lane = tid & 63;
  size_t base = (size_t)p * NN;
  double sj[4], bj[4];
  float acc[4];
#pragma unroll
  for (int k = 0; k < 4; ++k) {
    size_t idx = base + tid + k * 256;
    sj[k] = s[idx];
    bj[k] = B[idx];
    acc[k] = 0.f;
  }
  __shared__ float redm[KTOP][4];
  __shared__ float redz[KTOP][4];
  // pass 1: per-thread maxes for all 16 ranks, one batched reduction
  float mx[KTOP];
#pragma unroll
  for (int r = 0; r < KTOP; ++r) {
    double cr = (double)(1023 - 2 * r);
    float mv = -3.4e38f;
#pragma unroll
    for (int k = 0; k < 4; ++k) mv = fmaxf(mv, (float)fma(cr, sj[k], -bj[k]));
    mx[r] = mv;
  }
#pragma unroll
  for (int off = 32; off; off >>= 1) {
#pragma unroll
    for (int r = 0; r < KTOP; ++r)
      mx[r] = fmaxf(mx[r], __shfl_down(mx[r], off, 64));
  }
  if (lane == 0) {
#pragma unroll
    for (int r = 0; r < KTOP; ++r) redm[r][wave] = mx[r];
  }
  __syncthreads();
  float mf[KTOP];
#pragma unroll
  for (int r = 0; r < KTOP; ++r)
    mf[r] = fmaxf(fmaxf(redm[r][0], redm[r][1]),
                  fmaxf(redm[r][2], redm[r][3]));
  // pass 2: per-thread Z partials for all 16 ranks, one batched reduction
  float zz[KTOP];
#pragma unroll
  for (int r = 0; r < KTOP; ++r) {
    double cr = (double)(1023 - 2 * r);
    double md = (double)mf[r];
    float z = 0.f;
#pragma unroll
    for (int k = 0; k < 4; ++k)
      z += __expf((float)(fma(cr, sj[k], -bj[k]) - md));
    zz[r] = z;
  }
#pragma unroll
  for (int off = 32; off; off >>= 1) {
#pragma unroll
    for (int r = 0; r < KTOP; ++r) zz[r] += __shfl_down(zz[r], off, 64);
  }
  if (lane == 0) {
#pragma unroll
    for (int r = 0; r < KTOP; ++r) redz[r][wave] = zz[r];
  }
  __syncthreads();
  // pass 3: accumulate in original r order (bitwise-identical acc)
#pragma unroll
  for (int r = 0; r < KTOP; ++r) {
    double cr = (double)(1023 - 2 * r);
    double md = (double)mf[r];
    float iZ = 1.0f / ((redz[r][0] + redz[r][1]) + (redz[r][2] + redz[r][3]));
#pragma unroll
    for (int k = 0; k < 4; ++k)
      acc[k] += __expf((float)(fma(cr, sj[k], -bj[k]) - md)) * iZ;
  }
#pragma unroll
  for (int k = 0; k < 4; ++k) out[base + tid + k * 256] = acc[k];
}

extern "C" void kernel_launch(void* const* d_in, const int* in_sizes, int n_in,
                              void* d_out, int out_size, void* d_ws, size_t ws_size,
                              hipStream_t stream) {
  const float* q   = (const float*)d_in[0];   // [32,128]
  const float* nb  = (const float*)d_in[1];   // [1024,128]
  const float* gum = (const float*)d_in[2];   // [2,32,1024]
  float* out = (float*)d_out;                 // [2,32,1024]

  char* ws = (char*)d_ws;
  double* s = (double*)ws;                          // 512 KiB
  double* B = (double*)(ws + (size_t)NP * NN * 8);  // 512 KiB

  k_sb3<<<256, 1024, 0, stream>>>(q, nb, gum, s, B);
  k_soft<<<NP, 256, 0, stream>>>(s, B, out);
}

// Round 10
// 76.217 us; speedup vs baseline: 1.2313x; 1.2313x over previous
//
#include <hip/hip_runtime.h>

// DKNN via NeuralSort relaxation — round 12 (scalar-path k_bsum/k_scores).
// query [32,128] f32, neighbors [1024,128] f32, gumbel [2,32,1024] f32.
// out [2,32,1024] f32 = sum of first K=16 rows of relaxed perm matrix.
//
// Numerics FROZEN (absmax pinned at 0.0234375, bf16 compare). All operand
// VALUES and accumulation orders identical to R6 (bit-proven 75.7us):
//  - k_scores: (double)q[m*ND+d] used directly instead of via LDS qs[]
//    (same value, same subtraction, same a0..a3 chain).
//  - k_bsum: s[p*NN+iq*256+i] read directly from global instead of via LDS
//    ss[] (same value, same fabs/add chain, any-unroll preserves per-chain
//    order since a0..a3 assignment is by i&3).
//  - k_soft: byte-for-byte R6.
// => bitwise-identical output.
//
// R11 post-mortem: burst-register fusion spilled (WRITE_SIZE 21.5MB,
// VGPR=64) -> fused path abandoned; R6 3-kernel shape is right. Gap cost
// calibrated at ~2.5us/boundary (93.8 = 41 fill + 43 k_sb3 + 3 k_soft +
// ~7 gaps). Re-derived R6 budget: k_bsum ~19us = 5x its 3.4us issue floor
// -> latency-bound on ds_read_b64 + LDS stage + syncthreads at 4 waves/
// SIMD. Fix: the i-loop operand is WAVE-UNIFORM -> let the compiler
// scalarize it to s_load (SMEM pipe, no VALU/DS slots, prefetches deep);
// deletes the stage + sync + 256 ds_reads/wave. k_scores gets the same
// treatment for its uniform q row.

constexpr int NN = 1024;   // neighbors
constexpr int ND = 128;    // dims
constexpr int NP = 64;     // samples(2) * queries(32)
constexpr int KTOP = 16;

// ---------------------------------------------------------------- kernel 1
// s[p][j] = gumbel[p][j] - ||q_m - n_j||^2, all-f64. 256 blocks x 256 thr.
// q row is wave-uniform: read directly (scalarizable), no LDS, no sync.
__global__ __launch_bounds__(256) void k_scores(const float* __restrict__ q,
                                                const float* __restrict__ nb,
                                                const float* __restrict__ gum,
                                                double* __restrict__ s_out) {
  int b = blockIdx.x;
  int p = b >> 2, chunk = b & 3;
  int m = p & 31;
  int tid = threadIdx.x;
  int j = chunk * 256 + tid;
  const float4* nrow = (const float4*)(nb + (size_t)j * ND);
  const float* qrow = q + m * ND;   // uniform across the block
  double a0 = 0.0, a1 = 0.0, a2 = 0.0, a3 = 0.0;
#pragma unroll 8
  for (int d4 = 0; d4 < ND / 4; ++d4) {
    float4 n4 = nrow[d4];
    double d0 = (double)qrow[d4 * 4 + 0] - (double)n4.x;
    double d1 = (double)qrow[d4 * 4 + 1] - (double)n4.y;
    double d2 = (double)qrow[d4 * 4 + 2] - (double)n4.z;
    double d3 = (double)qrow[d4 * 4 + 3] - (double)n4.w;
    a0 += d0 * d0; a1 += d1 * d1; a2 += d2 * d2; a3 += d3 * d3;
  }
  s_out[(size_t)p * NN + j] =
      (double)gum[(size_t)p * NN + j] - ((a0 + a1) + (a2 + a3));
}

// ---------------------------------------------------------------- kernel 2
// B quarter-sums: Bq[iq][p][j] = sum_{i in quarter iq} |s_j - s_i|.
// grid = 64p * 4jchunk * 4iq = 1024 blocks x 256 thr (full device).
// i-loop operand is wave-uniform: direct global read (scalarizable),
// no LDS stage, no syncthreads.
__global__ __launch_bounds__(256) void k_bsum(const double* __restrict__ s,
                                              double* __restrict__ Bq) {
  int b = blockIdx.x;
  int p = b >> 4, jc = (b >> 2) & 3, iq = b & 3;
  int tid = threadIdx.x;
  const double* srow = s + (size_t)p * NN;   // uniform base
  double sj = srow[jc * 256 + tid];
  const double* sq = srow + iq * 256;        // uniform base, uniform index i
  double a0 = 0.0, a1 = 0.0, a2 = 0.0, a3 = 0.0;
#pragma unroll 8
  for (int i = 0; i < 256; i += 4) {
    a0 += fabs(sj - sq[i + 0]);
    a1 += fabs(sj - sq[i + 1]);
    a2 += fabs(sj - sq[i + 2]);
    a3 += fabs(sj - sq[i + 3]);
  }
  Bq[((size_t)iq * NP + p) * NN + jc * 256 + tid] = (a0 + a1) + (a2 + a3);
}

// ---------------------------------------------------------------- kernel 3
// Softmax-topk, exact R6 k_soft (2 barriers, batched reductions).
__global__ __launch_bounds__(256) void k_soft(const double* __restrict__ s,
                                              const double* __restrict__ Bq,
                                              float* __restrict__ out) {
  int p = blockIdx.x;
  int tid = threadIdx.x;
  int wave = tid >> 6, lane = tid & 63;
  const size_t QS = (size_t)NP * NN;
  size_t base = (size_t)p * NN;
  double sj[4], bj[4];
  float acc[4];
#pragma unroll
  for (int k = 0; k < 4; ++k) {
    size_t idx = base + tid + k * 256;
    sj[k] = s[idx];
    bj[k] = (Bq[idx] + Bq[QS + idx]) + (Bq[2 * QS + idx] + Bq[3 * QS + idx]);
    acc[k] = 0.f;
  }
  __shared__ float redm[KTOP][4];
  __shared__ float redz[KTOP][4];
  // pass 1: per-thread maxes for all 16 ranks, one batched reduction
  float mx[KTOP];
#pragma unroll
  for (int r = 0; r < KTOP; ++r) {
    double cr = (double)(1023 - 2 * r);
    float mv = -3.4e38f;
#pragma unroll
    for (int k = 0; k < 4; ++k) mv = fmaxf(mv, (float)fma(cr, sj[k], -bj[k]));
    mx[r] = mv;
  }
#pragma unroll
  for (int off = 32; off; off >>= 1) {
#pragma unroll
    for (int r = 0; r < KTOP; ++r)
      mx[r] = fmaxf(mx[r], __shfl_down(mx[r], off, 64));
  }
  if (lane == 0) {
#pragma unroll
    for (int r = 0; r < KTOP; ++r) redm[r][wave] = mx[r];
  }
  __syncthreads();
  float mf[KTOP];
#pragma unroll
  for (int r = 0; r < KTOP; ++r)
    mf[r] = fmaxf(fmaxf(redm[r][0], redm[r][1]),
                  fmaxf(redm[r][2], redm[r][3]));
  // pass 2: per-thread Z partials for all 16 ranks, one batched reduction
  float zz[KTOP];
#pragma unroll
  for (int r = 0; r < KTOP; ++r) {
    double cr = (double)(1023 - 2 * r);
    double md = (double)mf[r];
    float z = 0.f;
#pragma unroll
    for (int k = 0; k < 4; ++k)
      z += __expf((float)(fma(cr, sj[k], -bj[k]) - md));
    zz[r] = z;
  }
#pragma unroll
  for (int off = 32; off; off >>= 1) {
#pragma unroll
    for (int r = 0; r < KTOP; ++r) zz[r] += __shfl_down(zz[r], off, 64);
  }
  if (lane == 0) {
#pragma unroll
    for (int r = 0; r < KTOP; ++r) redz[r][wave] = zz[r];
  }
  __syncthreads();
  // pass 3: accumulate in original r order (bitwise-identical acc)
#pragma unroll
  for (int r = 0; r < KTOP; ++r) {
    double cr = (double)(1023 - 2 * r);
    double md = (double)mf[r];
    float iZ = 1.0f / ((redz[r][0] + redz[r][1]) + (redz[r][2] + redz[r][3]));
#pragma unroll
    for (int k = 0; k < 4; ++k)
      acc[k] += __expf((float)(fma(cr, sj[k], -bj[k]) - md)) * iZ;
  }
#pragma unroll
  for (int k = 0; k < 4; ++k) out[base + tid + k * 256] = acc[k];
}

extern "C" void kernel_launch(void* const* d_in, const int* in_sizes, int n_in,
                              void* d_out, int out_size, void* d_ws, size_t ws_size,
                              hipStream_t stream) {
  const float* q   = (const float*)d_in[0];   // [32,128]
  const float* nb  = (const float*)d_in[1];   // [1024,128]
  const float* gum = (const float*)d_in[2];   // [2,32,1024]
  float* out = (float*)d_out;                 // [2,32,1024]

  char* ws = (char*)d_ws;
  double* s  = (double*)ws;                              // 512 KiB
  double* Bq = (double*)(ws + (size_t)NP * NN * 8);      // 4 x 512 KiB

  k_scores<<<256, 256, 0, stream>>>(q, nb, gum, s);
  k_bsum<<<1024, 256, 0, stream>>>(s, Bq);
  k_soft<<<NP, 256, 0, stream>>>(s, Bq, out);
}